// Round 11
// baseline (235.045 us; speedup 1.0000x reference)
//
#include <hip/hip_runtime.h>
#include <stdint.h>

typedef unsigned short u16;
typedef __attribute__((ext_vector_type(8))) short short8;   // 8 bf16 = 4 VGPR
typedef __attribute__((ext_vector_type(4))) short s16x4;    // 4 bf16 = 2 VGPR
typedef __attribute__((ext_vector_type(4))) float f32x4;

#define MFMA16(a,b,c) __builtin_amdgcn_mfma_f32_16x16x32_bf16(a,b,c,0,0,0)

constexpr int B_ = 4, C_ = 512, N_ = 4096, D_ = 64;  // D_ = CQK = C/8

static __device__ __forceinline__ u16 f2bf(float f) {
    uint32_t u = __builtin_bit_cast(uint32_t, f);
    uint32_t r = (u + 0x7FFFu + ((u >> 16) & 1u)) >> 16;   // RNE
    return (u16)r;
}

// ---------------- prep: Wcat bf16 [640][512] + biascat; Wq/bq pre-scaled by log2(e) ----
__global__ void prep_w(const float* Wq, const float* bq, const float* Wk, const float* bk,
                       const float* Wv, const float* bv, u16* Wcat, float* biascat) {
    const float LOG2E = 1.44269504088896340736f;
    int idx = blockIdx.x * 256 + threadIdx.x;
    if (idx < 640 * 512) {
        int row = idx >> 9, col = idx & 511;
        float w;
        if (row < 64)        w = Wq[row * 512 + col] * LOG2E;
        else if (row < 128)  w = Wk[(row - 64) * 512 + col];
        else                 w = Wv[(row - 128) * 512 + col];
        Wcat[idx] = f2bf(w);
    }
    if (idx < 640) {
        float bb;
        if (idx < 64)        bb = bq[idx] * LOG2E;
        else if (idx < 128)  bb = bk[idx - 64];
        else                 bb = bv[idx - 128];
        biascat[idx] = bb;
    }
}

// ---------------- transpose x [B][C][N] f32 -> xT [B][N][C] bf16 ----------------
__global__ void transpose_x(const float* __restrict__ x, u16* __restrict__ xT) {
    __shared__ float tile[32][33];
    int n0 = blockIdx.x * 32, c0 = blockIdx.y * 32, b = blockIdx.z;
    int tx = threadIdx.x & 31, ty = threadIdx.x >> 5;       // ty 0..7
    const float* xb = x + (size_t)b * C_ * N_;
#pragma unroll
    for (int r = 0; r < 4; r++) {
        int c = ty * 4 + r;
        tile[c][tx] = xb[(size_t)(c0 + c) * N_ + n0 + tx];
    }
    __syncthreads();
    u16* xTb = xT + (size_t)b * N_ * C_;
#pragma unroll
    for (int r = 0; r < 4; r++) {
        int n = ty * 4 + r;
        xTb[(size_t)(n0 + n) * C_ + c0 + tx] = f2bf(tile[tx][n]);
    }
}

// ---------------- projection GEMM: Y[640][4096] = Wcat x X_b^T, per batch --------
__global__ __launch_bounds__(256) void proj_gemm(const u16* __restrict__ Wcat,
                                                 const float* __restrict__ biascat,
                                                 const u16* __restrict__ xT,
                                                 u16* __restrict__ qT, u16* __restrict__ kT,
                                                 u16* __restrict__ v) {
    int b = blockIdx.z;
    int m0 = blockIdx.y * 64;
    int wave = threadIdx.x >> 6, lane = threadIdx.x & 63;
    int n0 = blockIdx.x * 256 + wave * 64;
    int lr = lane & 15, lc = lane >> 4;
    const u16* xTb = xT + (size_t)b * N_ * C_;

    f32x4 acc[4][4] = {};   // [ma][na]
    short8 aF[4], bF[4], aFn[4], bFn[4];
#pragma unroll
    for (int ma = 0; ma < 4; ma++)
        aF[ma] = *reinterpret_cast<const short8*>(&Wcat[(size_t)(m0 + ma * 16 + lr) * 512 + lc * 8]);
#pragma unroll
    for (int na = 0; na < 4; na++)
        bF[na] = *reinterpret_cast<const short8*>(&xTb[(size_t)(n0 + na * 16 + lr) * 512 + lc * 8]);

    for (int k0 = 0; k0 < 512; k0 += 32) {
        if (k0 < 480) {
            int kn = k0 + 32;
#pragma unroll
            for (int ma = 0; ma < 4; ma++)
                aFn[ma] = *reinterpret_cast<const short8*>(&Wcat[(size_t)(m0 + ma * 16 + lr) * 512 + kn + lc * 8]);
#pragma unroll
            for (int na = 0; na < 4; na++)
                bFn[na] = *reinterpret_cast<const short8*>(&xTb[(size_t)(n0 + na * 16 + lr) * 512 + kn + lc * 8]);
        }
#pragma unroll
        for (int ma = 0; ma < 4; ma++)
#pragma unroll
            for (int na = 0; na < 4; na++)
                acc[ma][na] = MFMA16(aF[ma], bF[na], acc[ma][na]);
#pragma unroll
        for (int t = 0; t < 4; t++) { aF[t] = aFn[t]; bF[t] = bFn[t]; }
    }
#pragma unroll
    for (int ma = 0; ma < 4; ma++) {
#pragma unroll
        for (int r = 0; r < 4; r++) {
            int m = m0 + ma * 16 + lc * 4 + r;
            float bias = biascat[m];
#pragma unroll
            for (int na = 0; na < 4; na++) {
                int n = n0 + na * 16 + lr;
                u16 hv = f2bf(acc[ma][na][r] + bias);
                if (m < 64)
                    qT[((size_t)b * N_ + n) * D_ + m] = hv;
                else if (m < 128)
                    kT[((size_t)b * N_ + n) * D_ + (m - 64)] = hv;
                else
                    v[((size_t)b * C_ + (m - 128)) * (size_t)N_ + n] = hv;
            }
        }
    }
}

// ---------------- fused attention: full-j, c-split x2, small accumulator ----------------
// Grid 512 = (b, c-half, 64-i-tile); 8 waves; wave owns 64i x 32c (acc = 32 f32).
// 2 blocks/CU co-resident (R10: 46% occ proven). R11 deltas vs R10 (theory: phase
// serialization, not latency): (1) NO setprio -- prio-1 PV waves were starving the
// co-resident block's prio-0 S phase, defeating cross-block overlap; (2) Q in
// registers, not LDS (acc halved made room: ~102 total regs < 128) -- cuts LDS
// reads 24->16 b128/wave/jt; (3) post-barrier fence is a zero-cost asm memory
// clobber, not sched_barrier(0).
__global__ __launch_bounds__(512, 4) void attn(const u16* __restrict__ qT, const u16* __restrict__ kT,
                                               const u16* __restrict__ v, const float* __restrict__ x,
                                               const float* __restrict__ gamma_p, float* __restrict__ out) {
    int w = blockIdx.x;                 // [0,512)
    int xcd = w & 7, slot = w >> 3;     // slot in [0,64)
    int b = xcd >> 1;                   // XCD holds one (b, c-half): V-half 2MB + K 512KB in L2
    int c0 = (xcd & 1) * 256;
    int i0 = slot * 64;

    int wv = threadIdx.x >> 6, lane = threadIdx.x & 63;
    int lr = lane & 15, lc = lane >> 4;

    __shared__ u16 P_lds[2][64 * 128];  // 2 x 16KB, swizzled: byte = i*256 + (jb ^ ((i&7)<<4))
    __shared__ float s_l[64][8];        // per-wave partial row sums

    const u16* qTb = qT + (size_t)b * N_ * D_;
    const u16* kTb = kT + (size_t)b * N_ * D_;
    const u16* vb  = v  + (size_t)b * C_ * N_;

    // Q fragments: 64 i x 64 d, held in registers (B-operand: row=lr, k-chunk=lc*8)
    short8 qf[4][2];
#pragma unroll
    for (int mt = 0; mt < 4; mt++)
#pragma unroll
        for (int kd = 0; kd < 2; kd++)
            qf[mt][kd] = *reinterpret_cast<const short8*>(
                &qTb[(size_t)(i0 + mt * 16 + lr) * D_ + kd * 32 + lc * 8]);

    f32x4 acc[4][2] = {};               // [mt][ct]: O slice 64 i x 32 c (unnormalized)
    float lsum[4] = {0.f, 0.f, 0.f, 0.f};

    for (int jt = 0; jt < 32; jt++) {
        char* pb = reinterpret_cast<char*>(P_lds[jt & 1]);

        // ---- K for this tile (single-buffer; stalls covered by co-resident block) ----
        const u16* kp = kTb + (size_t)(jt * 128 + wv * 16 + lr) * D_;
        short8 kf0 = *reinterpret_cast<const short8*>(kp + lc * 8);
        short8 kf1 = *reinterpret_cast<const short8*>(kp + 32 + lc * 8);

        // ---- S phase: swapped mfma(K,Q): lane holds S'[i=mt*16+lr][j=wv*16+lc*4+r] ----
#pragma unroll
        for (int mt = 0; mt < 4; mt++) {
            f32x4 s = {};
            s = MFMA16(kf0, qf[mt][0], s);
            s = MFMA16(kf1, qf[mt][1], s);
            s16x4 pk;
            float ps = 0.f;
#pragma unroll
            for (int r = 0; r < 4; r++) {
                float p = __builtin_amdgcn_exp2f(s[r]);   // exp(q.k): log2e folded into Wq
                ps += p;
                pk[r] = (short)f2bf(p);
            }
            lsum[mt] += ps;
            int i = mt * 16 + lr;
            int byte_off = i * 256 + ((wv * 32 + lc * 8) ^ ((i & 7) << 4));
            *reinterpret_cast<s16x4*>(pb + byte_off) = pk;
        }

        // ---- barrier WITHOUT vmcnt drain: drain own LDS writes, raw barrier, then a
        //      zero-cost compiler memory fence (ds_reads must not hoist above) ----
        asm volatile("s_waitcnt lgkmcnt(0)" ::: "memory");
        __builtin_amdgcn_s_barrier();
        asm volatile("" ::: "memory");

        // ---- PV phase: O[64 i][32 c] += P[64][128] * V[c][128 j]; V streamed at use ----
#pragma unroll
        for (int kt = 0; kt < 4; kt++) {
            short8 pf[4];
#pragma unroll
            for (int mt = 0; mt < 4; mt++) {
                int i = mt * 16 + lr;
                int byte_off = i * 256 + (((kt * 64) + lc * 16) ^ ((i & 7) << 4));
                pf[mt] = *reinterpret_cast<const short8*>(pb + byte_off);
            }
#pragma unroll
            for (int ct = 0; ct < 2; ct++) {
                short8 vf = *reinterpret_cast<const short8*>(
                    &vb[(size_t)(c0 + wv * 32 + ct * 16 + lr) * N_ + jt * 128 + kt * 32 + lc * 8]);
#pragma unroll
                for (int mt = 0; mt < 4; mt++)
                    acc[mt][ct] = MFMA16(pf[mt], vf, acc[mt][ct]);
            }
        }
    }

    // ---- row-sum reduce across lanes, then waves -> s_l ----
#pragma unroll
    for (int mt = 0; mt < 4; mt++) {
        float l_ = lsum[mt];
        l_ += __shfl_xor(l_, 16);
        l_ += __shfl_xor(l_, 32);
        if (lc == 0) s_l[mt * 16 + lr][wv] = l_;
    }
    __syncthreads();

    // ---- epilogue: out = gamma * (O / l) + x (direct, full j-range per block) ----
    float g = gamma_p[0];
    const float* xb = x + (size_t)b * C_ * N_;
    float* ob = out + (size_t)b * C_ * N_;
#pragma unroll
    for (int mt = 0; mt < 4; mt++) {
        float linv[4];
#pragma unroll
        for (int r = 0; r < 4; r++) {
            int i = mt * 16 + lc * 4 + r;
            float4 l0 = *reinterpret_cast<const float4*>(&s_l[i][0]);
            float4 l1 = *reinterpret_cast<const float4*>(&s_l[i][4]);
            linv[r] = 1.0f / (l0.x + l0.y + l0.z + l0.w + l1.x + l1.y + l1.z + l1.w);
        }
#pragma unroll
        for (int ct = 0; ct < 2; ct++) {
            int c = c0 + wv * 32 + ct * 16 + lr;
            size_t off = (size_t)c * N_ + i0 + mt * 16 + lc * 4;
            float4 xv = *reinterpret_cast<const float4*>(&xb[off]);
            float4 ov;
            ov.x = g * acc[mt][ct][0] * linv[0] + xv.x;
            ov.y = g * acc[mt][ct][1] * linv[1] + xv.y;
            ov.z = g * acc[mt][ct][2] * linv[2] + xv.z;
            ov.w = g * acc[mt][ct][3] * linv[3] + xv.w;
            *reinterpret_cast<float4*>(&ob[off]) = ov;
        }
    }
}

extern "C" void kernel_launch(void* const* d_in, const int* in_sizes, int n_in,
                              void* d_out, int out_size, void* d_ws, size_t ws_size,
                              hipStream_t stream) {
    const float* x     = (const float*)d_in[0];
    const float* Wq    = (const float*)d_in[1];
    const float* bq    = (const float*)d_in[2];
    const float* Wk    = (const float*)d_in[3];
    const float* bk    = (const float*)d_in[4];
    const float* Wv    = (const float*)d_in[5];
    const float* bv    = (const float*)d_in[6];
    const float* gamma = (const float*)d_in[7];
    float* out = (float*)d_out;

    char* ws = (char*)d_ws;
    // layout (bytes): xT 16MB | Wcat 640KB | biascat 4KB | qT 2MB | kT 2MB | v 16MB
    u16*   xT      = (u16*)ws;
    u16*   Wcat    = (u16*)(ws + (size_t)16777216);
    float* biascat = (float*)(ws + (size_t)16777216 + 655360);
    u16*   qT      = (u16*)(ws + (size_t)16777216 + 655360 + 4096);
    u16*   kT      = qT + (size_t)B_ * N_ * D_;
    u16*   v       = kT + (size_t)B_ * N_ * D_;

    prep_w<<<1280, 256, 0, stream>>>(Wq, bq, Wk, bk, Wv, bv, Wcat, biascat);
    transpose_x<<<dim3(N_ / 32, C_ / 32, B_), 256, 0, stream>>>(x, xT);
    proj_gemm<<<dim3(N_ / 256, 640 / 64, B_), 256, 0, stream>>>(Wcat, biascat, xT, qT, kT, v);
    attn<<<512, 512, 0, stream>>>(qT, kT, v, x, gamma, out);
}

// Round 12
// 191.166 us; speedup vs baseline: 1.2295x; 1.2295x over previous
//
#include <hip/hip_runtime.h>
#include <stdint.h>

typedef unsigned short u16;
typedef unsigned int u32;
typedef __attribute__((ext_vector_type(8))) short short8;   // 8 bf16 = 4 VGPR
typedef __attribute__((ext_vector_type(4))) short s16x4;
typedef __attribute__((ext_vector_type(4))) float f32x4;
typedef __attribute__((ext_vector_type(16))) float f32x16;
typedef __attribute__((ext_vector_type(4))) int int4v;

#define MFMA16(a,b,c) __builtin_amdgcn_mfma_f32_16x16x32_bf16(a,b,c,0,0,0)
#define MFMA32(a,b,c) __builtin_amdgcn_mfma_f32_32x32x16_bf16(a,b,c,0,0,0)

constexpr int B_ = 4, C_ = 512, N_ = 4096, D_ = 64;  // D_ = CQK = C/8

static __device__ __forceinline__ u16 f2bf(float f) {
    uint32_t u = __builtin_bit_cast(uint32_t, f);
    uint32_t r = (u + 0x7FFFu + ((u >> 16) & 1u)) >> 16;   // RNE
    return (u16)r;
}

// ---------------- prep: Wcat bf16 [640][512] + biascat; Wq/bq pre-scaled by log2(e) ----
__global__ void prep_w(const float* Wq, const float* bq, const float* Wk, const float* bk,
                       const float* Wv, const float* bv, u16* Wcat, float* biascat) {
    const float LOG2E = 1.44269504088896340736f;
    int idx = blockIdx.x * 256 + threadIdx.x;
    if (idx < 640 * 512) {
        int row = idx >> 9, col = idx & 511;
        float w;
        if (row < 64)        w = Wq[row * 512 + col] * LOG2E;
        else if (row < 128)  w = Wk[(row - 64) * 512 + col];
        else                 w = Wv[(row - 128) * 512 + col];
        Wcat[idx] = f2bf(w);
    }
    if (idx < 640) {
        float bb;
        if (idx < 64)        bb = bq[idx] * LOG2E;
        else if (idx < 128)  bb = bk[idx - 64];
        else                 bb = bv[idx - 128];
        biascat[idx] = bb;
    }
}

// ---------------- transpose x [B][C][N] f32 -> xT [B][N][C] bf16 ----------------
__global__ void transpose_x(const float* __restrict__ x, u16* __restrict__ xT) {
    __shared__ float tile[32][33];
    int n0 = blockIdx.x * 32, c0 = blockIdx.y * 32, b = blockIdx.z;
    int tx = threadIdx.x & 31, ty = threadIdx.x >> 5;       // ty 0..7
    const float* xb = x + (size_t)b * C_ * N_;
#pragma unroll
    for (int r = 0; r < 4; r++) {
        int c = ty * 4 + r;
        tile[c][tx] = xb[(size_t)(c0 + c) * N_ + n0 + tx];
    }
    __syncthreads();
    u16* xTb = xT + (size_t)b * N_ * C_;
#pragma unroll
    for (int r = 0; r < 4; r++) {
        int n = ty * 4 + r;
        xTb[(size_t)(n0 + n) * C_ + c0 + tx] = f2bf(tile[tx][n]);
    }
}

// ---------------- projection GEMM: Y[640][4096] = Wcat x X_b^T, per batch --------
__global__ __launch_bounds__(256) void proj_gemm(const u16* __restrict__ Wcat,
                                                 const float* __restrict__ biascat,
                                                 const u16* __restrict__ xT,
                                                 u16* __restrict__ qT, u16* __restrict__ kT,
                                                 u16* __restrict__ v) {
    int b = blockIdx.z;
    int m0 = blockIdx.y * 64;
    int wave = threadIdx.x >> 6, lane = threadIdx.x & 63;
    int n0 = blockIdx.x * 256 + wave * 64;
    int lr = lane & 15, lc = lane >> 4;
    const u16* xTb = xT + (size_t)b * N_ * C_;

    f32x4 acc[4][4] = {};
    short8 aF[4], bF[4], aFn[4], bFn[4];
#pragma unroll
    for (int ma = 0; ma < 4; ma++)
        aF[ma] = *reinterpret_cast<const short8*>(&Wcat[(size_t)(m0 + ma * 16 + lr) * 512 + lc * 8]);
#pragma unroll
    for (int na = 0; na < 4; na++)
        bF[na] = *reinterpret_cast<const short8*>(&xTb[(size_t)(n0 + na * 16 + lr) * 512 + lc * 8]);

    for (int k0 = 0; k0 < 512; k0 += 32) {
        if (k0 < 480) {
            int kn = k0 + 32;
#pragma unroll
            for (int ma = 0; ma < 4; ma++)
                aFn[ma] = *reinterpret_cast<const short8*>(&Wcat[(size_t)(m0 + ma * 16 + lr) * 512 + kn + lc * 8]);
#pragma unroll
            for (int na = 0; na < 4; na++)
                bFn[na] = *reinterpret_cast<const short8*>(&xTb[(size_t)(n0 + na * 16 + lr) * 512 + kn + lc * 8]);
        }
#pragma unroll
        for (int ma = 0; ma < 4; ma++)
#pragma unroll
            for (int na = 0; na < 4; na++)
                acc[ma][na] = MFMA16(aF[ma], bF[na], acc[ma][na]);
#pragma unroll
        for (int t = 0; t < 4; t++) { aF[t] = aFn[t]; bF[t] = bFn[t]; }
    }
#pragma unroll
    for (int ma = 0; ma < 4; ma++) {
#pragma unroll
        for (int r = 0; r < 4; r++) {
            int m = m0 + ma * 16 + lc * 4 + r;
            float bias = biascat[m];
#pragma unroll
            for (int na = 0; na < 4; na++) {
                int n = n0 + na * 16 + lr;
                u16 hv = f2bf(acc[ma][na][r] + bias);
                if (m < 64)
                    qT[((size_t)b * N_ + n) * D_ + m] = hv;
                else if (m < 128)
                    kT[((size_t)b * N_ + n) * D_ + (m - 64)] = hv;
                else
                    v[((size_t)b * C_ + (m - 128)) * (size_t)N_ + n] = hv;
            }
        }
    }
}

// ---------------- fused attention: wave-independent S (x4 dup), in-register P ----------------
// 256 blocks x 512 thr, 1 block/CU. Block = (b, 256-i super-tile, 128-c slice); the 8
// waves each own 32 i-rows and ALL 128 c; each wave computes its OWN S for every j
// (QK^T duplicated x4 across c-slices) -> P never crosses waves -> NO producer/consumer
// chain through the barrier. K (8KB) & V (32KB) tiles of 64 j double-buffered in
// XOR-swizzled LDS; the one barrier/jt only guards staging buffers (GEMM T3 pattern).
// P goes f32 -> bf16 A-fragments IN-REGISTER: v_cvt_pk_bf16_f32 + shfl_xor(32) + sel
// (T12 / m214 layout: swapped mfma32 puts row i=lane&31 in-lane; crow(r,hi)=(r&3)+8*(r>>2)+4*hi).
__global__ __launch_bounds__(512, 2) void attn(const u16* __restrict__ qT, const u16* __restrict__ kT,
                                               const u16* __restrict__ v, const float* __restrict__ x,
                                               const float* __restrict__ gamma_p, float* __restrict__ out) {
    int blk = blockIdx.x;               // [0,256)
    int xcd = blk & 7, rest = blk >> 3; // rest in [0,32)
    int b = xcd >> 1;
    int cs = (xcd & 1) + 2 * (rest & 1);    // c-slice 0..3 (XCD L2: 2 V-slices + K = 2.5MB)
    int isuper = rest >> 1;                  // 0..15
    int c0 = cs * 128;
    int ib0 = isuper * 256;

    int wv = threadIdx.x >> 6, lane = threadIdx.x & 63;
    int li = lane & 31, hi = lane >> 5;

    __shared__ char smem[49152];
    char* Kb0 = smem;                    // [64 j][128B, swz ^((j&7)<<4)]
    char* Kb1 = smem + 8192;
    char* Vb0 = smem + 16384;            // [128 c][128B, swz ^((c&7)<<4)]
    char* Vb1 = smem + 32768;

    const u16* qTb = qT + (size_t)b * N_ * D_;
    const u16* kTb = kT + (size_t)b * N_ * D_;
    const u16* vb  = v  + (size_t)b * C_ * N_;

    // Q fragments (B-operand, 32x32x16: row=li=i, k=hi*8+e), 4 d-chunks of 16
    short8 qf[4];
#pragma unroll
    for (int dc = 0; dc < 4; dc++)
        qf[dc] = *reinterpret_cast<const short8*>(
            &qTb[(size_t)(ib0 + wv * 32 + li) * D_ + dc * 16 + hi * 8]);

    f32x16 acc[4] = {};                 // [ct]: O[32 i][c = ct*32+li], i=crow(r,hi)
    float lsum = 0.f;

    // staging lane roles
    int ksj = wv * 8 + (lane >> 3);     // K row j (64 rows / 8 waves / 8 octets)
    int ksd = (lane & 7) * 8;           // K d-elem
    int kwoff = ksj * 128 + ((ksd * 2) ^ ((ksj & 7) << 4));
    int vsc = wv * 16 + (lane >> 3);    // V row c (q adds +8)
    int vsj = (lane & 7) * 8;           // V j-elem
    int vwoff0 = vsc * 128 + ((vsj * 2) ^ ((vsc & 7) << 4));
    int vwoff1 = (vsc + 8) * 128 + ((vsj * 2) ^ (((vsc + 8) & 7) << 4));

    // prologue: stage tile 0
    {
        short8 k0 = *reinterpret_cast<const short8*>(&kTb[(size_t)ksj * D_ + ksd]);
        short8 v0 = *reinterpret_cast<const short8*>(&vb[(size_t)(c0 + vsc) * N_ + vsj]);
        short8 v1 = *reinterpret_cast<const short8*>(&vb[(size_t)(c0 + vsc + 8) * N_ + vsj]);
        *reinterpret_cast<short8*>(Kb0 + kwoff) = k0;
        *reinterpret_cast<short8*>(Vb0 + vwoff0) = v0;
        *reinterpret_cast<short8*>(Vb0 + vwoff1) = v1;
    }
    __syncthreads();

    int swz = (li & 7) << 4;
    for (int jt = 0; jt < 64; jt++) {
        char* Kc = (jt & 1) ? Kb1 : Kb0;
        char* Vc = (jt & 1) ? Vb1 : Vb0;
        char* Kn = (jt & 1) ? Kb0 : Kb1;
        char* Vn = (jt & 1) ? Vb0 : Vb1;

        // ---- issue next tile's staging loads (consumed by ds_write below) ----
        short8 kst, vst0, vst1;
        if (jt < 63) {
            int j1 = (jt + 1) * 64;
            kst  = *reinterpret_cast<const short8*>(&kTb[(size_t)(j1 + ksj) * D_ + ksd]);
            vst0 = *reinterpret_cast<const short8*>(&vb[(size_t)(c0 + vsc) * N_ + j1 + vsj]);
            vst1 = *reinterpret_cast<const short8*>(&vb[(size_t)(c0 + vsc + 8) * N_ + j1 + vsj]);
        }

        // ---- compute this tile: 2 j-chunks of 32, fully wave-local ----
#pragma unroll
        for (int jc = 0; jc < 2; jc++) {
            int j0 = jc * 32;
            short8 kf0 = *reinterpret_cast<const short8*>(Kc + (j0 + li) * 128 + ((0   + hi * 16) ^ swz));
            short8 kf1 = *reinterpret_cast<const short8*>(Kc + (j0 + li) * 128 + ((32  + hi * 16) ^ swz));
            short8 kf2 = *reinterpret_cast<const short8*>(Kc + (j0 + li) * 128 + ((64  + hi * 16) ^ swz));
            short8 kf3 = *reinterpret_cast<const short8*>(Kc + (j0 + li) * 128 + ((96  + hi * 16) ^ swz));
            f32x16 S = {};
            S = MFMA32(kf0, qf[0], S);
            S = MFMA32(kf1, qf[1], S);
            S = MFMA32(kf2, qf[2], S);
            S = MFMA32(kf3, qf[3], S);
            // p = exp(S) (log2e folded into Wq); lane holds row i=li, j=crow(r,hi)+j0
            float p[16];
#pragma unroll
            for (int r = 0; r < 16; r++) p[r] = __builtin_amdgcn_exp2f(S[r]);
            lsum += (((p[0]+p[1])+(p[2]+p[3]))+((p[4]+p[5])+(p[6]+p[7])))
                  + (((p[8]+p[9])+(p[10]+p[11]))+((p[12]+p[13])+(p[14]+p[15])));
            // pack to bf16 pairs: w[k] = {p[2k], p[2k+1]}
            u32 w[8];
#pragma unroll
            for (int k = 0; k < 8; k++)
                asm("v_cvt_pk_bf16_f32 %0, %1, %2" : "=v"(w[k]) : "v"(p[2 * k]), "v"(p[2 * k + 1]));
            // assemble PV A-fragments (row=li, k=hi*8+e) via one lane-32 exchange
            u32 s0 = hi ? w[0] : w[2], s1 = hi ? w[1] : w[3];
            u32 s2 = hi ? w[4] : w[6], s3 = hi ? w[5] : w[7];
            u32 x0 = __shfl_xor((int)s0, 32), x1 = __shfl_xor((int)s1, 32);
            u32 x2 = __shfl_xor((int)s2, 32), x3 = __shfl_xor((int)s3, 32);
            int4v pa0 = { (int)(hi ? x0 : w[0]), (int)(hi ? x1 : w[1]),
                          (int)(hi ? w[2] : x0), (int)(hi ? w[3] : x1) };
            int4v pa1 = { (int)(hi ? x2 : w[4]), (int)(hi ? x3 : w[5]),
                          (int)(hi ? w[6] : x2), (int)(hi ? w[7] : x3) };
            short8 PA0 = __builtin_bit_cast(short8, pa0);   // j = j0 + hi*8+e
            short8 PA1 = __builtin_bit_cast(short8, pa1);   // j = j0+16 + hi*8+e
            // PV: O[i][c] += P[i][j] * V[c][j]
#pragma unroll
            for (int ct = 0; ct < 4; ct++) {
                const char* vrow = Vc + (ct * 32 + li) * 128;
                short8 vf0 = *reinterpret_cast<const short8*>(vrow + ((jc * 64 + hi * 16) ^ swz));
                short8 vf1 = *reinterpret_cast<const short8*>(vrow + ((jc * 64 + 32 + hi * 16) ^ swz));
                acc[ct] = MFMA32(PA0, vf0, acc[ct]);
                acc[ct] = MFMA32(PA1, vf1, acc[ct]);
            }
        }

        // ---- write staged regs into the other buffer, then the only barrier ----
        if (jt < 63) {
            *reinterpret_cast<short8*>(Kn + kwoff) = kst;
            *reinterpret_cast<short8*>(Vn + vwoff0) = vst0;
            *reinterpret_cast<short8*>(Vn + vwoff1) = vst1;
        }
        __syncthreads();
    }

    // ---- finalize: row sums, normalize, transpose via per-wave LDS, residual ----
    float lfull = lsum + __shfl_xor(lsum, 32);   // full row-sum for i=li
    float g = gamma_p[0];
    float* olds = reinterpret_cast<float*>(smem + wv * 4608);   // [32 c][36] f32
    const float* xb = x + (size_t)b * C_ * N_;
    float* ob = out + (size_t)b * C_ * N_;
#pragma unroll
    for (int ct = 0; ct < 4; ct++) {
#pragma unroll
        for (int r = 0; r < 16; r++) {
            int crow = (r & 3) + 8 * (r >> 2) + 4 * hi;     // i-local
            float linv = 1.0f / __shfl(lfull, crow);
            olds[li * 36 + crow] = g * acc[ct][r] * linv;
        }
        asm volatile("s_waitcnt lgkmcnt(0)" ::: "memory");
#pragma unroll
        for (int cp = 0; cp < 4; cp++) {
            int c_l = cp * 8 + (lane >> 3);
            int i4 = (lane & 7) * 4;
            float4 o4 = *reinterpret_cast<const float4*>(&olds[c_l * 36 + i4]);
            size_t off = (size_t)(c0 + ct * 32 + c_l) * N_ + ib0 + wv * 32 + i4;
            float4 xv = *reinterpret_cast<const float4*>(&xb[off]);
            float4 ov = { o4.x + xv.x, o4.y + xv.y, o4.z + xv.z, o4.w + xv.w };
            *reinterpret_cast<float4*>(&ob[off]) = ov;
        }
        asm volatile("s_waitcnt lgkmcnt(0)" ::: "memory");
    }
}

extern "C" void kernel_launch(void* const* d_in, const int* in_sizes, int n_in,
                              void* d_out, int out_size, void* d_ws, size_t ws_size,
                              hipStream_t stream) {
    const float* x     = (const float*)d_in[0];
    const float* Wq    = (const float*)d_in[1];
    const float* bq    = (const float*)d_in[2];
    const float* Wk    = (const float*)d_in[3];
    const float* bk    = (const float*)d_in[4];
    const float* Wv    = (const float*)d_in[5];
    const float* bv    = (const float*)d_in[6];
    const float* gamma = (const float*)d_in[7];
    float* out = (float*)d_out;

    char* ws = (char*)d_ws;
    // layout (bytes): xT 16MB | Wcat 640KB | biascat 4KB | qT 2MB | kT 2MB | v 16MB
    u16*   xT      = (u16*)ws;
    u16*   Wcat    = (u16*)(ws + (size_t)16777216);
    float* biascat = (float*)(ws + (size_t)16777216 + 655360);
    u16*   qT      = (u16*)(ws + (size_t)16777216 + 655360 + 4096);
    u16*   kT      = qT + (size_t)B_ * N_ * D_;
    u16*   v       = kT + (size_t)B_ * N_ * D_;

    prep_w<<<1280, 256, 0, stream>>>(Wq, bq, Wk, bk, Wv, bv, Wcat, biascat);
    transpose_x<<<dim3(N_ / 32, C_ / 32, B_), 256, 0, stream>>>(x, xT);
    proj_gemm<<<dim3(N_ / 256, 640 / 64, B_), 256, 0, stream>>>(Wcat, biascat, xT, qT, kT, v);
    attn<<<256, 512, 0, stream>>>(qT, kT, v, x, gamma, out);
}